// Round 2
// baseline (731.352 us; speedup 1.0000x reference)
//
#include <hip/hip_runtime.h>
#include <hip/hip_bf16.h>

#define N_NODES 10000
#define E_TOT   320000

typedef __attribute__((ext_vector_type(8))) short short8;
typedef __attribute__((ext_vector_type(4))) float f32x4;

// ---- workspace byte offsets (all 16B-aligned) ----
#define AGG_S_OFF   0u            // N*256 f32 = 10,240,000 B
#define AGG_V_OFF   10240000u     // N*96  f32 =  3,840,000 B
#define CNT_OFF     14080000u     // N     f32 =     40,000 B
#define ZERO_BYTES  14120000u     // memset range [0, here)
#define PQ_OFF      14120192u     // N*408 f32 = 16,320,000 B   P|Q per node
#define PVQV_OFF    30440192u     // N*192 f32 =  7,680,000 B   Pv|Qv per node
#define NS2_OFF     38120192u     // N*256 f32 = 10,240,000 B   node_s @ W[320:576]
#define WHV4_OFF    48360192u     // 128 f32   =        512 B   wh[32:36]@wv
#define WT_OFF      48360704u     // 256*416 bf16 = 212,992 B   W' transposed [n][k]
#define VN_OFF      48573696u     // E*96 bf16 = 61,440,000 B   vn padded to 96/row
#define FLAGS_OFF   110013696u    // 2 ints: [0]=f32-mode, [1]=int64-mode

union BfS { __hip_bfloat16 h; short s; };
__device__ __forceinline__ short f2bf(float x) { BfS u; u.h = __float2bfloat16(x); return u.s; }
__device__ __forceinline__ float ldin(const void* p, int f32m, long i) {
  return f32m ? ((const float*)p)[i] : __bfloat162float(((const __hip_bfloat16*)p)[i]);
}
__device__ __forceinline__ int get_ei(const void* p, int i64m, long i) {
  return i64m ? (int)(((const long long*)p)[i]) : ((const int*)p)[i];
}

// ---------------------------------------------------------------------------
// detect: decide input float dtype (bf16 vs f32) and index dtype (i32 vs i64)
// from the raw bytes. Deterministic given inputs -> graph-capture safe.
// ---------------------------------------------------------------------------
__global__ __launch_bounds__(256) void detect_kernel(
    const unsigned short* __restrict__ ns_u16,
    const int* __restrict__ ei_i32, int* __restrict__ flags)
{
  __shared__ int cf, ci;
  if (threadIdx.x == 0) { cf = 0; ci = 0; }
  __syncthreads();
  int c1 = 0;
  for (int i = threadIdx.x; i < 8192; i += 256) {
    unsigned e = (ns_u16[2 * i] >> 7) & 0xFF;   // even u16 = f32 low half if f32
    if (e < 100 || e > 140) c1++;               // valid bf16 N(0,1): never
  }
  int c2 = 0;
  for (int i = threadIdx.x; i < 4096; i += 256)
    if (ei_i32[2 * i + 1] != 0) c2++;           // int64 hi-words are all zero
  atomicAdd(&cf, c1); atomicAdd(&ci, c2);
  __syncthreads();
  if (threadIdx.x == 0) {
    flags[0] = (cf > 512) ? 1 : 0;   // 1 => inputs are f32
    flags[1] = (ci < 100) ? 1 : 0;   // 1 => edge_index is int64
  }
}

// ---------------------------------------------------------------------------
// prep: build Wt[n][k] bf16 (k<256: src rows, 256..319: edge rows,
// 320..387: vn rows 576..643 of ws_w, >=388: zero). Block 416: whv4.
// ---------------------------------------------------------------------------
__global__ __launch_bounds__(256) void prep_kernel(
    const void* __restrict__ ws_w, const void* __restrict__ wh,
    const void* __restrict__ wv, const int* __restrict__ flags,
    short* __restrict__ Wt, float* __restrict__ whv4)
{
  const int f32m = flags[0];
  int b = blockIdx.x, tid = threadIdx.x;
  if (b < 416) {
    int flat = b * 256 + tid;           // = n*416 + k
    int n = flat / 416, k = flat % 416;
    short v = 0;
    if (k < 320)      v = f2bf(ldin(ws_w, f32m, (long)k * 256 + n));
    else if (k < 388) v = f2bf(ldin(ws_w, f32m, (long)(k + 256) * 256 + n));
    Wt[flat] = v;
  } else if (tid < 128) {
    int q = tid / 32, c = tid % 32;
    float acc = 0.f;
    for (int h = 0; h < 68; ++h)
      acc += ldin(wh, f32m, (32 + q) * 68 + h) * ldin(wv, f32m, h * 32 + c);
    whv4[tid] = acc;
  }
}

// ---------------------------------------------------------------------------
// node_pre: per 4 nodes — P,Q (node_v^T @ wh halves), Pv,Qv (@wv), ns2.
// ---------------------------------------------------------------------------
__global__ __launch_bounds__(256) void node_pre(
    const void* __restrict__ node_s, const void* __restrict__ node_v,
    const void* __restrict__ wh, const void* __restrict__ wv,
    const void* __restrict__ ws_w, const int* __restrict__ flags,
    float* __restrict__ PQ, float* __restrict__ PvQv, float* __restrict__ ns2)
{
  const int f32m = flags[0];
  int n0 = blockIdx.x * 4, tid = threadIdx.x;
  __shared__ float nv[4][96];
  __shared__ float nsl[4][256];
  __shared__ float pq[4][408];
  for (int i = tid; i < 4 * 96; i += 256)  nv[i / 96][i % 96]    = ldin(node_v, f32m, (long)n0 * 96 + i);
  for (int i = tid; i < 4 * 256; i += 256) nsl[i / 256][i % 256] = ldin(node_s, f32m, (long)n0 * 256 + i);
  __syncthreads();
  for (int o = tid; o < 4 * 408; o += 256) {
    int i = o / 408, r0 = o % 408;
    int part = r0 / 204, r = r0 % 204, d = r / 68, h = r % 68;
    int cbase = part ? 36 : 0;
    float acc = 0.f;
#pragma unroll
    for (int c = 0; c < 32; ++c)
      acc += nv[i][c * 3 + d] * ldin(wh, f32m, (cbase + c) * 68 + h);
    pq[i][r0] = acc;
    PQ[(long)(n0 + i) * 408 + r0] = acc;
  }
  __syncthreads();
  for (int o = tid; o < 4 * 192; o += 256) {
    int i = o / 192, r0 = o % 192;
    int part = r0 / 96, r = r0 % 96, d = r / 32, c = r % 32;
    float acc = 0.f;
    for (int h = 0; h < 68; ++h)
      acc += pq[i][part * 204 + d * 68 + h] * ldin(wv, f32m, h * 32 + c);
    PvQv[(long)(n0 + i) * 192 + r0] = acc;
  }
  {
    float a0 = 0.f, a1 = 0.f, a2 = 0.f, a3 = 0.f;
    for (int k = 0; k < 256; ++k) {
      float w = ldin(ws_w, f32m, (long)(320 + k) * 256 + tid);
      a0 += nsl[0][k] * w; a1 += nsl[1][k] * w;
      a2 += nsl[2][k] * w; a3 += nsl[3][k] * w;
    }
    ns2[(long)(n0 + 0) * 256 + tid] = a0; ns2[(long)(n0 + 1) * 256 + tid] = a1;
    ns2[(long)(n0 + 2) * 256 + tid] = a2; ns2[(long)(n0 + 3) * 256 + tid] = a3;
  }
}

// ---------------------------------------------------------------------------
// edge_light: per 8 edges — vn (norm of P[src]+R_e+Q[dst]), v_msg scatter, cnt.
// ---------------------------------------------------------------------------
__global__ __launch_bounds__(256) void edge_light(
    const void* __restrict__ edge_v, const void* __restrict__ wh,
    const void* __restrict__ edge_index, const int* __restrict__ flags,
    const float* __restrict__ PQ, const float* __restrict__ PvQv,
    const float* __restrict__ whv4,
    float* __restrict__ agg_v, float* __restrict__ cnt,
    __hip_bfloat16* __restrict__ vn_out)
{
  const int f32m = flags[0], i64m = flags[1];
  int tid = threadIdx.x;
  int e0 = blockIdx.x * 8;
  __shared__ float whs4[4 * 68];
  __shared__ float whv4s[128];
  __shared__ float ev[8 * 12];     // [e][q][d]
  __shared__ int sv[8], dv[8];
  for (int i = tid; i < 272; i += 256) whs4[i] = ldin(wh, f32m, (32 + i / 68) * 68 + (i % 68));
  if (tid < 128) whv4s[tid] = whv4[tid];
  for (int i = tid; i < 96; i += 256) ev[i] = ldin(edge_v, f32m, (long)e0 * 12 + i);
  if (tid < 8) { sv[tid] = get_ei(edge_index, i64m, e0 + tid);
                 dv[tid] = get_ei(edge_index, i64m, (long)E_TOT + e0 + tid); }
  __syncthreads();
  for (int o = tid; o < 8 * 68; o += 256) {
    int e = o / 68, h = o % 68;
    int s = sv[e], dn = dv[e];
    float ss = 0.f;
#pragma unroll
    for (int d = 0; d < 3; ++d) {
      float v = PQ[(long)s * 408 + d * 68 + h] + PQ[(long)dn * 408 + 204 + d * 68 + h];
      v += ev[e * 12 + 0 + d] * whs4[0 * 68 + h] + ev[e * 12 + 3 + d] * whs4[1 * 68 + h]
         + ev[e * 12 + 6 + d] * whs4[2 * 68 + h] + ev[e * 12 + 9 + d] * whs4[3 * 68 + h];
      ss += v * v;
    }
    vn_out[(long)(e0 + e) * 96 + h] = __float2bfloat16(sqrtf(fmaxf(ss, 1e-8f)));
  }
  for (int o = tid; o < 8 * 28; o += 256) {
    int e = o / 28, h = 68 + o % 28;
    vn_out[(long)(e0 + e) * 96 + h] = __float2bfloat16(0.f);
  }
  for (int o = tid; o < 8 * 96; o += 256) {
    int e = o / 96, r = o % 96, c = r / 3, d = r % 3;
    int s = sv[e], dn = dv[e];
    float val = PvQv[(long)s * 192 + d * 32 + c];
    val += ev[e * 12 + 0 + d] * whv4s[0 + c]  + ev[e * 12 + 3 + d] * whv4s[32 + c]
         + ev[e * 12 + 6 + d] * whv4s[64 + c] + ev[e * 12 + 9 + d] * whv4s[96 + c];
    atomicAdd(&agg_v[(long)dn * 96 + r], val);
  }
  if (tid < 8) atomicAdd(&cnt[dv[tid]], 1.0f);
}

// ---------------------------------------------------------------------------
// gemm_scatter: [E,388(pad416)] @ W' -> [E,256], MFMA 16x16x32 bf16,
// 64x256 tile/block, 4 waves, each wave: 4 row-frags x 4 col-tiles.
// X row = [node_s[src] | edge_s | vn]. Scatter-add rows to agg_s[dst].
// ---------------------------------------------------------------------------
__global__ __launch_bounds__(256) void gemm_scatter(
    const void* __restrict__ node_s, const void* __restrict__ edge_s,
    const short* __restrict__ Wt,          // [256][416] bf16 bits
    const short* __restrict__ vn_ws,       // [E][96] bf16 bits
    const void* __restrict__ edge_index, const int* __restrict__ flags,
    float* __restrict__ agg_s)
{
  __shared__ __align__(16) short Xs[64 * 40];   // stride 40: 2-way alias (free)
  __shared__ __align__(16) short Ws[256 * 40];
  __shared__ int srcv[64], dstv[64];
  const int tid = threadIdx.x;
  const int e0 = blockIdx.x * 64;
  const int f32m = flags[0], i64m = flags[1];
  if (tid < 64) {
    srcv[tid] = get_ei(edge_index, i64m, e0 + tid);
    dstv[tid] = get_ei(edge_index, i64m, (long)E_TOT + e0 + tid);
  }
  __syncthreads();
  const int lane = tid & 63, wave = tid >> 6;
  const int frow = lane & 15, fk = (lane >> 4) * 8;
  f32x4 acc[4][4];
#pragma unroll
  for (int ri = 0; ri < 4; ++ri)
#pragma unroll
    for (int ci = 0; ci < 4; ++ci)
      acc[ri][ci] = (f32x4){0.f, 0.f, 0.f, 0.f};

  const int se = tid >> 2;   // edge row 0..63
  const int sq = tid & 3;    // 8-elem chunk

  for (int s = 0; s < 13; ++s) {
    short8 xv;
    if (s < 10) {
      long off = (s < 8) ? ((long)srcv[se] * 256 + s * 32 + sq * 8)
                         : ((long)(e0 + se) * 64 + (s - 8) * 32 + sq * 8);
      const void* base = (s < 8) ? node_s : edge_s;
      if (f32m) {
        const float* pf = (const float*)base + off;
        f32x4 lo = *(const f32x4*)pf, hi = *(const f32x4*)(pf + 4);
        xv[0] = f2bf(lo[0]); xv[1] = f2bf(lo[1]); xv[2] = f2bf(lo[2]); xv[3] = f2bf(lo[3]);
        xv[4] = f2bf(hi[0]); xv[5] = f2bf(hi[1]); xv[6] = f2bf(hi[2]); xv[7] = f2bf(hi[3]);
      } else {
        xv = *(const short8*)((const short*)base + off);
      }
    } else {
      xv = *(const short8*)(vn_ws + (long)(e0 + se) * 96 + (s - 10) * 32 + sq * 8);
    }
    *(short8*)&Xs[se * 40 + sq * 8] = xv;
#pragma unroll
    for (int it = 0; it < 4; ++it) {
      int flat = it * 256 + tid;
      int n = flat >> 2, q = flat & 3;
      *(short8*)&Ws[n * 40 + q * 8] = *(const short8*)&Wt[n * 416 + s * 32 + q * 8];
    }
    __syncthreads();
    short8 a[4];
#pragma unroll
    for (int ri = 0; ri < 4; ++ri)
      a[ri] = *(const short8*)&Xs[(ri * 16 + frow) * 40 + fk];
#pragma unroll
    for (int ci = 0; ci < 4; ++ci) {
      int n = wave * 64 + ci * 16 + frow;
      short8 b = *(const short8*)&Ws[n * 40 + fk];
#pragma unroll
      for (int ri = 0; ri < 4; ++ri)
        acc[ri][ci] = __builtin_amdgcn_mfma_f32_16x16x32_bf16(a[ri], b, acc[ri][ci], 0, 0, 0);
    }
    __syncthreads();
  }
  // D[row][col]: row=(lane>>4)*4+r (+16*ri), col=lane&15 (+16*ci+64*wave)
#pragma unroll
  for (int ri = 0; ri < 4; ++ri) {
#pragma unroll
    for (int r = 0; r < 4; ++r) {
      int row = ri * 16 + (lane >> 4) * 4 + r;
      int dn = dstv[row];
#pragma unroll
      for (int ci = 0; ci < 4; ++ci) {
        int col = wave * 64 + ci * 16 + (lane & 15);
        atomicAdd(&agg_s[(long)dn * 256 + col], acc[ri][ci][r]);
      }
    }
  }
}

// ---------------------------------------------------------------------------
// finalize: out[n][0:256] = agg_s/c + ns2 + b ; out[n][256:352] = agg_v/c + Qv
// (per-dst-constant terms only when cnt>0, matching max(cnt,1) reference).
// ---------------------------------------------------------------------------
__global__ __launch_bounds__(256) void finalize(
    const float* __restrict__ agg_s, const float* __restrict__ agg_v,
    const float* __restrict__ cnt, const float* __restrict__ ns2,
    const float* __restrict__ PvQv, const void* __restrict__ ws_b,
    const int* __restrict__ flags, void* __restrict__ out)
{
  const int f32m = flags[0];
  int flat = blockIdx.x * 256 + threadIdx.x;   // N*352 = 3,520,000 exact
  int n = flat / 352, j = flat % 352;
  float c = cnt[n];
  float inv = 1.f / fmaxf(c, 1.f);
  float v;
  if (j < 256) {
    v = agg_s[(long)n * 256 + j] * inv;
    if (c > 0.f) v += ns2[(long)n * 256 + j] + ldin(ws_b, f32m, j);
  } else {
    int m = j - 256, ch = m / 3, d = m % 3;
    v = agg_v[(long)n * 96 + m] * inv;
    if (c > 0.f) v += PvQv[(long)n * 192 + 96 + d * 32 + ch];   // Qv[n][d][ch]
  }
  if (f32m) ((float*)out)[flat] = v;
  else      ((__hip_bfloat16*)out)[flat] = __float2bfloat16(v);
}

extern "C" void kernel_launch(void* const* d_in, const int* in_sizes, int n_in,
                              void* d_out, int out_size, void* d_ws, size_t ws_size,
                              hipStream_t stream) {
  const void* node_s = d_in[0];
  const void* node_v = d_in[1];
  const void* edge_s = d_in[2];
  const void* edge_v = d_in[3];
  const void* wh     = d_in[4];
  const void* ws_w   = d_in[5];
  const void* ws_b   = d_in[6];
  const void* wv     = d_in[7];
  const void* edge_index = d_in[8];

  char* ws = (char*)d_ws;
  float* agg_s = (float*)(ws + AGG_S_OFF);
  float* agg_v = (float*)(ws + AGG_V_OFF);
  float* cnt   = (float*)(ws + CNT_OFF);
  float* PQ    = (float*)(ws + PQ_OFF);
  float* PvQv  = (float*)(ws + PVQV_OFF);
  float* ns2   = (float*)(ws + NS2_OFF);
  float* whv4  = (float*)(ws + WHV4_OFF);
  short* Wt    = (short*)(ws + WT_OFF);
  __hip_bfloat16* vn = (__hip_bfloat16*)(ws + VN_OFF);
  int* flags   = (int*)(ws + FLAGS_OFF);

  hipMemsetAsync(d_ws, 0, ZERO_BYTES, stream);
  detect_kernel<<<1, 256, 0, stream>>>((const unsigned short*)node_s,
                                       (const int*)edge_index, flags);
  prep_kernel<<<417, 256, 0, stream>>>(ws_w, wh, wv, flags, Wt, whv4);
  node_pre<<<2500, 256, 0, stream>>>(node_s, node_v, wh, wv, ws_w, flags,
                                     PQ, PvQv, ns2);
  edge_light<<<40000, 256, 0, stream>>>(edge_v, wh, edge_index, flags,
                                        PQ, PvQv, whv4, agg_v, cnt, vn);
  gemm_scatter<<<5000, 256, 0, stream>>>(node_s, edge_s, Wt, (const short*)vn,
                                         edge_index, flags, agg_s);
  finalize<<<13750, 256, 0, stream>>>(agg_s, agg_v, cnt, ns2, PvQv, ws_b,
                                      flags, (__hip_bfloat16*)d_out);
}

// Round 4
// 673.519 us; speedup vs baseline: 1.0859x; 1.0859x over previous
//
#include <hip/hip_runtime.h>
#include <hip/hip_bf16.h>

#define N_NODES 10000
#define E_TOT   320000

typedef __attribute__((ext_vector_type(8))) short short8;
typedef __attribute__((ext_vector_type(4))) float f32x4;

// ---- workspace byte offsets (16B-aligned, NO overlaps) ----
#define AGG_S_OFF   0u            // N*256 f32 = 10,240,000
#define AGG_V_OFF   10240000u     // N*96  f32 =  3,840,000 (direct-written)
#define HIST_OFF    14080000u     // N int = 40,000
#define FILL_OFF    14120000u     // N int = 40,000
#define ZERO_BYTES  14160000u     // memset [0, here)
#define ROWPTR_OFF  14160064u     // (N+1) int = 40,004 -> padded to 14,200,128
#define PERM_OFF    14200128u     // E int = 1,280,000
#define PSRC_OFF    15480128u     // E int
#define PDST_OFF    16760128u     // E int
#define PQ_OFF      18040128u     // N*408 bf16 = 8,160,000   P|Q per node
#define PVQV_OFF    26200128u     // N*192 bf16 = 3,840,000   Pv|Qv per node
#define NS2_OFF     30040128u     // N*256 f32 = 10,240,000
#define WHV4_OFF    40280128u     // 128 f32 = 512
#define WT_OFF      40280640u     // 256*416 bf16 = 212,992
#define NSBF_OFF    40493632u     // N*256 bf16 = 5,120,000
#define VN_OFF      45613632u     // E*96 bf16 = 61,440,000 (sorted order)
#define FLAGS_OFF   107053632u    // 2 ints

union BfS { __hip_bfloat16 h; short s; };
__device__ __forceinline__ short f2bf(float x) { BfS u; u.h = __float2bfloat16(x); return u.s; }
__device__ __forceinline__ float bf(short x) { BfS u; u.s = x; return __bfloat162float(u.h); }
__device__ __forceinline__ float ldin(const void* p, int f32m, long i) {
  return f32m ? ((const float*)p)[i] : __bfloat162float(((const __hip_bfloat16*)p)[i]);
}
__device__ __forceinline__ int get_ei(const void* p, int i64m, long i) {
  return i64m ? (int)(((const long long*)p)[i]) : ((const int*)p)[i];
}

// ---------------------------------------------------------------------------
__global__ __launch_bounds__(256) void detect_kernel(
    const unsigned short* __restrict__ ns_u16,
    const int* __restrict__ ei_i32, int* __restrict__ flags)
{
  __shared__ int cf, ci;
  if (threadIdx.x == 0) { cf = 0; ci = 0; }
  __syncthreads();
  int c1 = 0;
  for (int i = threadIdx.x; i < 8192; i += 256) {
    unsigned e = (ns_u16[2 * i] >> 7) & 0xFF;
    if (e < 100 || e > 140) c1++;
  }
  int c2 = 0;
  for (int i = threadIdx.x; i < 4096; i += 256)
    if (ei_i32[2 * i + 1] != 0) c2++;
  atomicAdd(&cf, c1); atomicAdd(&ci, c2);
  __syncthreads();
  if (threadIdx.x == 0) {
    flags[0] = (cf > 512) ? 1 : 0;   // 1 => f32 inputs
    flags[1] = (ci < 100) ? 1 : 0;   // 1 => int64 edge_index
  }
}

// ---------------------------------------------------------------------------
__global__ __launch_bounds__(256) void hist_kernel(
    const void* __restrict__ edge_index, const int* __restrict__ flags,
    int* __restrict__ hist)
{
  const int i64m = flags[1];
  int e = blockIdx.x * 256 + threadIdx.x;
  int dst = get_ei(edge_index, i64m, (long)E_TOT + e);
  atomicAdd(&hist[dst], 1);
}

__global__ __launch_bounds__(256) void scan_kernel(
    const int* __restrict__ hist, int* __restrict__ rowptr)
{
  __shared__ int part[256];
  int tid = threadIdx.x;
  int base = tid * 40;
  int s = 0;
  for (int i = 0; i < 40; ++i) { int idx = base + i; if (idx < N_NODES) s += hist[idx]; }
  part[tid] = s;
  __syncthreads();
  for (int off = 1; off < 256; off <<= 1) {
    int v = (tid >= off) ? part[tid - off] : 0;
    __syncthreads();
    part[tid] += v;
    __syncthreads();
  }
  int run = (tid > 0) ? part[tid - 1] : 0;
  for (int i = 0; i < 40; ++i) {
    int idx = base + i;
    if (idx < N_NODES) { rowptr[idx] = run; run += hist[idx]; }
  }
  if (tid == 255) rowptr[N_NODES] = run;
}

__global__ __launch_bounds__(256) void permute_kernel(
    const void* __restrict__ edge_index, const int* __restrict__ flags,
    const int* __restrict__ rowptr, int* __restrict__ fill,
    int* __restrict__ perm, int* __restrict__ psrc, int* __restrict__ pdst)
{
  const int i64m = flags[1];
  int e = blockIdx.x * 256 + threadIdx.x;
  int dst = get_ei(edge_index, i64m, (long)E_TOT + e);
  int src = get_ei(edge_index, i64m, e);
  int pos = rowptr[dst] + atomicAdd(&fill[dst], 1);
  perm[pos] = e; psrc[pos] = src; pdst[pos] = dst;
}

// ---------------------------------------------------------------------------
// prep: Wt[n][k] bf16 (k<256: src rows; 256..319: edge rows; 320..387: vn
// rows 576..643 of ws_w; >=388: 0). Block 416: whv4 = wh[32:36]@wv.
// ---------------------------------------------------------------------------
__global__ __launch_bounds__(256) void prep_kernel(
    const void* __restrict__ ws_w, const void* __restrict__ wh,
    const void* __restrict__ wv, const int* __restrict__ flags,
    short* __restrict__ Wt, float* __restrict__ whv4)
{
  const int f32m = flags[0];
  int b = blockIdx.x, tid = threadIdx.x;
  if (b < 416) {
    int flat = b * 256 + tid;
    int n = flat / 416, k = flat % 416;
    short v = 0;
    if (k < 320)      v = f2bf(ldin(ws_w, f32m, (long)k * 256 + n));
    else if (k < 388) v = f2bf(ldin(ws_w, f32m, (long)(k + 256) * 256 + n));
    Wt[flat] = v;
  } else if (tid < 128) {
    int q = tid / 32, c = tid % 32;
    float acc = 0.f;
    for (int h = 0; h < 68; ++h)
      acc += ldin(wh, f32m, (32 + q) * 68 + h) * ldin(wv, f32m, h * 32 + c);
    whv4[tid] = acc;
  }
}

__global__ __launch_bounds__(256) void nsconv_kernel(
    const void* __restrict__ node_s, const int* __restrict__ flags,
    short* __restrict__ ns_bf)
{
  const int f32m = flags[0];
  int i = blockIdx.x * 256 + threadIdx.x;   // N*256 = 2,560,000 exact
  ns_bf[i] = f2bf(ldin(node_s, f32m, i));
}

// ---------------------------------------------------------------------------
// node_pre: per 4 nodes — P,Q (node_v^T @ wh halves) bf16, Pv,Qv bf16, ns2 f32.
// ---------------------------------------------------------------------------
__global__ __launch_bounds__(256) void node_pre(
    const void* __restrict__ node_s, const void* __restrict__ node_v,
    const void* __restrict__ wh, const void* __restrict__ wv,
    const void* __restrict__ ws_w, const int* __restrict__ flags,
    short* __restrict__ PQ, short* __restrict__ PvQv, float* __restrict__ ns2)
{
  const int f32m = flags[0];
  int n0 = blockIdx.x * 4, tid = threadIdx.x;
  __shared__ float nv[4][96];
  __shared__ float nsl[4][256];
  __shared__ float pq[4][408];
  for (int i = tid; i < 4 * 96; i += 256)  nv[i / 96][i % 96]    = ldin(node_v, f32m, (long)n0 * 96 + i);
  for (int i = tid; i < 4 * 256; i += 256) nsl[i / 256][i % 256] = ldin(node_s, f32m, (long)n0 * 256 + i);
  __syncthreads();
  for (int o = tid; o < 4 * 408; o += 256) {
    int i = o / 408, r0 = o % 408;
    int part = r0 / 204, r = r0 % 204, d = r / 68, h = r % 68;
    int cbase = part ? 36 : 0;
    float acc = 0.f;
#pragma unroll
    for (int c = 0; c < 32; ++c)
      acc += nv[i][c * 3 + d] * ldin(wh, f32m, (cbase + c) * 68 + h);
    pq[i][r0] = acc;
    PQ[(long)(n0 + i) * 408 + r0] = f2bf(acc);
  }
  __syncthreads();
  for (int o = tid; o < 4 * 192; o += 256) {
    int i = o / 192, r0 = o % 192;
    int part = r0 / 96, r = r0 % 96, d = r / 32, c = r % 32;
    float acc = 0.f;
    for (int h = 0; h < 68; ++h)
      acc += pq[i][part * 204 + d * 68 + h] * ldin(wv, f32m, h * 32 + c);
    PvQv[(long)(n0 + i) * 192 + r0] = f2bf(acc);
  }
  {
    float a0 = 0.f, a1 = 0.f, a2 = 0.f, a3 = 0.f;
    for (int k = 0; k < 256; ++k) {
      float w = ldin(ws_w, f32m, (long)(320 + k) * 256 + tid);
      a0 += nsl[0][k] * w; a1 += nsl[1][k] * w;
      a2 += nsl[2][k] * w; a3 += nsl[3][k] * w;
    }
    ns2[(long)(n0 + 0) * 256 + tid] = a0; ns2[(long)(n0 + 1) * 256 + tid] = a1;
    ns2[(long)(n0 + 2) * 256 + tid] = a2; ns2[(long)(n0 + 3) * 256 + tid] = a3;
  }
}

// ---------------------------------------------------------------------------
// edge_csr: one block per dst node. Q[n] staged once; vn written at SORTED
// position; agg_v direct-written (no atomics).
// ---------------------------------------------------------------------------
__global__ __launch_bounds__(256) void edge_csr(
    const void* __restrict__ edge_v, const void* __restrict__ wh,
    const float* __restrict__ whv4, const int* __restrict__ flags,
    const int* __restrict__ rowptr, const int* __restrict__ perm,
    const int* __restrict__ psrc,
    const short* __restrict__ PQbf, const short* __restrict__ PvQvbf,
    float* __restrict__ agg_v, short* __restrict__ vn_out)
{
  const int f32m = flags[0];
  const int n = blockIdx.x, tid = threadIdx.x;
  const int beg = rowptr[n], deg = rowptr[n + 1] - beg;
  __shared__ float Qs[204], whs4[272], whv4s[128];
  __shared__ float ev[32 * 12];
  __shared__ int sv[32], eidv[32];
  for (int i = tid; i < 204; i += 256) Qs[i] = bf(PQbf[(long)n * 408 + 204 + i]);
  for (int i = tid; i < 272; i += 256) whs4[i] = ldin(wh, f32m, (32 + i / 68) * 68 + (i % 68));
  if (tid < 128) whv4s[tid] = whv4[tid];
  __syncthreads();
  const int rc = tid / 3, rd = tid % 3;   // for v_msg phase (tid<96)
  float accr = 0.f;
  for (int c0 = 0; c0 < deg; c0 += 32) {
    int m = min(32, deg - c0);
    if (tid < m) { sv[tid] = psrc[beg + c0 + tid]; eidv[tid] = perm[beg + c0 + tid]; }
    __syncthreads();
    for (int i = tid; i < m * 12; i += 256)
      ev[i] = ldin(edge_v, f32m, (long)eidv[i / 12] * 12 + i % 12);
    __syncthreads();
    // vn
    for (int o = tid; o < m * 68; o += 256) {
      int e = o / 68, h = o % 68, s = sv[e];
      float ss = 0.f;
#pragma unroll
      for (int d3 = 0; d3 < 3; ++d3) {
        float v = bf(PQbf[(long)s * 408 + d3 * 68 + h]) + Qs[d3 * 68 + h]
                + ev[e * 12 + 0 + d3] * whs4[h]        + ev[e * 12 + 3 + d3] * whs4[68 + h]
                + ev[e * 12 + 6 + d3] * whs4[136 + h]  + ev[e * 12 + 9 + d3] * whs4[204 + h];
        ss += v * v;
      }
      vn_out[(long)(beg + c0 + e) * 96 + h] = f2bf(sqrtf(fmaxf(ss, 1e-8f)));
    }
    for (int o = tid; o < m * 28; o += 256)
      vn_out[(long)(beg + c0 + o / 28) * 96 + 68 + o % 28] = 0;
    // v_msg accumulate (thread t<96 owns output r=t; no atomics)
    if (tid < 96) {
      float a = 0.f;
      for (int e = 0; e < m; ++e) {
        int s = sv[e];
        a += bf(PvQvbf[(long)s * 192 + rd * 32 + rc])
           + ev[e * 12 + 0 + rd] * whv4s[rc]      + ev[e * 12 + 3 + rd] * whv4s[32 + rc]
           + ev[e * 12 + 6 + rd] * whv4s[64 + rc] + ev[e * 12 + 9 + rd] * whv4s[96 + rc];
      }
      accr += a;
    }
    __syncthreads();
  }
  if (tid < 96) agg_v[(long)n * 96 + tid] = accr;
}

// ---------------------------------------------------------------------------
// gemm_scatter over SORTED edges: [E,388(pad416)] @ W' -> [E,256] with
// per-lane dst-run merge in the epilogue (sorted dsts => ~6x fewer atomics).
// ---------------------------------------------------------------------------
__global__ __launch_bounds__(256) void gemm_scatter(
    const short* __restrict__ ns_bf, const void* __restrict__ edge_s,
    const short* __restrict__ Wt, const short* __restrict__ vn_ws,
    const int* __restrict__ perm, const int* __restrict__ psrc,
    const int* __restrict__ pdst, const int* __restrict__ flags,
    float* __restrict__ agg_s)
{
  __shared__ __align__(16) short Xs[64 * 40];
  __shared__ __align__(16) short Ws[256 * 40];
  __shared__ int srcv[64], dstv[64], eidv[64];
  const int tid = threadIdx.x;
  const int e0 = blockIdx.x * 64;
  const int f32m = flags[0];
  if (tid < 64) {
    srcv[tid] = psrc[e0 + tid];
    dstv[tid] = pdst[e0 + tid];
    eidv[tid] = perm[e0 + tid];
  }
  __syncthreads();
  const int lane = tid & 63, wave = tid >> 6;
  const int frow = lane & 15, fk = (lane >> 4) * 8, q = lane >> 4;
  f32x4 acc[4][4];
#pragma unroll
  for (int ri = 0; ri < 4; ++ri)
#pragma unroll
    for (int ci = 0; ci < 4; ++ci)
      acc[ri][ci] = (f32x4){0.f, 0.f, 0.f, 0.f};

  const int se = tid >> 2;
  const int sq = tid & 3;

  for (int s = 0; s < 13; ++s) {
    short8 xv;
    if (s < 8) {
      xv = *(const short8*)&ns_bf[(long)srcv[se] * 256 + s * 32 + sq * 8];
    } else if (s < 10) {
      long off = (long)eidv[se] * 64 + (s - 8) * 32 + sq * 8;
      if (f32m) {
        const float* pf = (const float*)edge_s + off;
        f32x4 lo = *(const f32x4*)pf, hi = *(const f32x4*)(pf + 4);
        xv[0] = f2bf(lo[0]); xv[1] = f2bf(lo[1]); xv[2] = f2bf(lo[2]); xv[3] = f2bf(lo[3]);
        xv[4] = f2bf(hi[0]); xv[5] = f2bf(hi[1]); xv[6] = f2bf(hi[2]); xv[7] = f2bf(hi[3]);
      } else {
        xv = *(const short8*)((const short*)edge_s + off);
      }
    } else {
      xv = *(const short8*)&vn_ws[(long)(e0 + se) * 96 + (s - 10) * 32 + sq * 8];
    }
    *(short8*)&Xs[se * 40 + sq * 8] = xv;
#pragma unroll
    for (int it = 0; it < 4; ++it) {
      int flat = it * 256 + tid;
      int nn = flat >> 2, qq = flat & 3;
      *(short8*)&Ws[nn * 40 + qq * 8] = *(const short8*)&Wt[nn * 416 + s * 32 + qq * 8];
    }
    __syncthreads();
    short8 a[4];
#pragma unroll
    for (int ri = 0; ri < 4; ++ri)
      a[ri] = *(const short8*)&Xs[(ri * 16 + frow) * 40 + fk];
#pragma unroll
    for (int ci = 0; ci < 4; ++ci) {
      int nn = wave * 64 + ci * 16 + frow;
      short8 b = *(const short8*)&Ws[nn * 40 + fk];
#pragma unroll
      for (int ri = 0; ri < 4; ++ri)
        acc[ri][ci] = __builtin_amdgcn_mfma_f32_16x16x32_bf16(a[ri], b, acc[ri][ci], 0, 0, 0);
    }
    __syncthreads();
  }
  // epilogue: lane owns rows {16*ri + 4*q + rr} (monotone); dsts sorted ->
  // merge equal-dst runs before the atomic.
#pragma unroll
  for (int ci = 0; ci < 4; ++ci) {
    int col = wave * 64 + ci * 16 + (lane & 15);
    float run = 0.f;
    int cur = dstv[4 * q];
#pragma unroll
    for (int ri = 0; ri < 4; ++ri) {
#pragma unroll
      for (int rr = 0; rr < 4; ++rr) {
        int dn = dstv[16 * ri + 4 * q + rr];
        if (dn != cur) {
          atomicAdd(&agg_s[(long)cur * 256 + col], run);
          run = 0.f; cur = dn;
        }
        run += acc[ri][ci][rr];
      }
    }
    atomicAdd(&agg_s[(long)cur * 256 + col], run);
  }
}

// ---------------------------------------------------------------------------
__global__ __launch_bounds__(256) void finalize(
    const float* __restrict__ agg_s, const float* __restrict__ agg_v,
    const int* __restrict__ rowptr, const float* __restrict__ ns2,
    const short* __restrict__ PvQvbf, const void* __restrict__ ws_b,
    const int* __restrict__ flags, void* __restrict__ out)
{
  const int f32m = flags[0];
  int flat = blockIdx.x * 256 + threadIdx.x;   // N*352 exact
  int n = flat / 352, j = flat % 352;
  int deg = rowptr[n + 1] - rowptr[n];
  float c = (float)deg;
  float inv = 1.f / fmaxf(c, 1.f);
  float v;
  if (j < 256) {
    v = agg_s[(long)n * 256 + j] * inv;
    if (deg > 0) v += ns2[(long)n * 256 + j] + ldin(ws_b, f32m, j);
  } else {
    int m = j - 256, ch = m / 3, d = m % 3;
    v = agg_v[(long)n * 96 + m] * inv;
    if (deg > 0) v += bf(PvQvbf[(long)n * 192 + 96 + d * 32 + ch]);
  }
  if (f32m) ((float*)out)[flat] = v;
  else      ((__hip_bfloat16*)out)[flat] = __float2bfloat16(v);
}

extern "C" void kernel_launch(void* const* d_in, const int* in_sizes, int n_in,
                              void* d_out, int out_size, void* d_ws, size_t ws_size,
                              hipStream_t stream) {
  const void* node_s = d_in[0];
  const void* node_v = d_in[1];
  const void* edge_s = d_in[2];
  const void* edge_v = d_in[3];
  const void* wh     = d_in[4];
  const void* ws_w   = d_in[5];
  const void* ws_b   = d_in[6];
  const void* wv     = d_in[7];
  const void* edge_index = d_in[8];

  char* ws = (char*)d_ws;
  float* agg_s = (float*)(ws + AGG_S_OFF);
  float* agg_v = (float*)(ws + AGG_V_OFF);
  int*   hist  = (int*)(ws + HIST_OFF);
  int*   fill  = (int*)(ws + FILL_OFF);
  int*   rowptr= (int*)(ws + ROWPTR_OFF);
  int*   perm  = (int*)(ws + PERM_OFF);
  int*   psrc  = (int*)(ws + PSRC_OFF);
  int*   pdst  = (int*)(ws + PDST_OFF);
  short* PQ    = (short*)(ws + PQ_OFF);
  short* PvQv  = (short*)(ws + PVQV_OFF);
  float* ns2   = (float*)(ws + NS2_OFF);
  float* whv4  = (float*)(ws + WHV4_OFF);
  short* Wt    = (short*)(ws + WT_OFF);
  short* ns_bf = (short*)(ws + NSBF_OFF);
  short* vn    = (short*)(ws + VN_OFF);
  int*   flags = (int*)(ws + FLAGS_OFF);

  hipMemsetAsync(d_ws, 0, ZERO_BYTES, stream);
  detect_kernel<<<1, 256, 0, stream>>>((const unsigned short*)node_s,
                                       (const int*)edge_index, flags);
  hist_kernel<<<1250, 256, 0, stream>>>(edge_index, flags, hist);
  scan_kernel<<<1, 256, 0, stream>>>(hist, rowptr);
  permute_kernel<<<1250, 256, 0, stream>>>(edge_index, flags, rowptr, fill,
                                           perm, psrc, pdst);
  prep_kernel<<<417, 256, 0, stream>>>(ws_w, wh, wv, flags, Wt, whv4);
  nsconv_kernel<<<10000, 256, 0, stream>>>(node_s, flags, ns_bf);
  node_pre<<<2500, 256, 0, stream>>>(node_s, node_v, wh, wv, ws_w, flags,
                                     PQ, PvQv, ns2);
  edge_csr<<<10000, 256, 0, stream>>>(edge_v, wh, whv4, flags, rowptr, perm,
                                      psrc, PQ, PvQv, agg_v, vn);
  gemm_scatter<<<5000, 256, 0, stream>>>(ns_bf, edge_s, Wt, vn, perm, psrc,
                                         pdst, flags, agg_s);
  finalize<<<13750, 256, 0, stream>>>(agg_s, agg_v, rowptr, ns2, PvQv, ws_b,
                                      flags, d_out);
}